// Round 8
// baseline (426.190 us; speedup 1.0000x reference)
//
#include <hip/hip_runtime.h>
#include <hip/hip_bf16.h>
#include <stdint.h>
#include <stddef.h>

using bf16x8 = __attribute__((ext_vector_type(8))) short;
using f32x4  = __attribute__((ext_vector_type(4))) float;
using f32x16 = __attribute__((ext_vector_type(16))) float;

#define DEV static __device__ __forceinline__

DEV unsigned short f2bf(float f) {
  union { float f; uint32_t u; } x; x.f = f;
  uint32_t u = x.u;
  u += 0x7fffu + ((u >> 16) & 1u);   // RNE
  return (unsigned short)(u >> 16);
}

DEV uint32_t pkbf(float a, float b) {   // packs to [b:a] (lo=a) -> v_cvt_pk_bf16_f32
  __hip_bfloat162 t = __float22bfloat162_rn(float2{a, b});
  union { __hip_bfloat162 h; uint32_t u; } c; c.h = t; return c.u;
}

DEV void gld_lds16(const void* g, void* lds) {
  __builtin_amdgcn_global_load_lds(
      (__attribute__((address_space(1))) void*)(uintptr_t)g,
      (__attribute__((address_space(3))) void*)(uintptr_t)lds, 16, 0, 0);
}

// -------- weight transpose: fp32 [K][N] -> bf16 [N][K] --------
__global__ void transpose_w(const float* __restrict__ in, unsigned short* __restrict__ out,
                            int K, int N) {
  __shared__ float tile[64][65];
  int n0 = blockIdx.x * 64, k0 = blockIdx.y * 64;
  int tx = threadIdx.x & 15, ty = threadIdx.x >> 4;
#pragma unroll
  for (int j = 0; j < 4; ++j) {
    int r = ty + j * 16;
    float4 v = *(const float4*)(in + (size_t)(k0 + r) * N + n0 + tx * 4);
    tile[r][tx * 4 + 0] = v.x; tile[r][tx * 4 + 1] = v.y;
    tile[r][tx * 4 + 2] = v.z; tile[r][tx * 4 + 3] = v.w;
  }
  __syncthreads();
#pragma unroll
  for (int j = 0; j < 4; ++j) {
    int n = ty + j * 16;
    ushort4 o;
    o.x = f2bf(tile[tx * 4 + 0][n]);
    o.y = f2bf(tile[tx * 4 + 1][n]);
    o.z = f2bf(tile[tx * 4 + 2][n]);
    o.w = f2bf(tile[tx * 4 + 3][n]);
    *(ushort4*)(out + (size_t)(n0 + n) * K + k0 + tx * 4) = o;
  }
}

__global__ void pack_bias(const float* __restrict__ q, const float* __restrict__ k,
                          const float* __restrict__ v, float* __restrict__ out) {
  int i = blockIdx.x * 256 + threadIdx.x;   // 0..2303
  const float* s = (i < 768) ? q : ((i < 1536) ? k : v);
  int r = i; if (r >= 1536) r -= 1536; else if (r >= 768) r -= 768;
  out[i] = s[r];
}

// -------- LayerNorm: wave per row, fp32 in -> bf16 out --------
__global__ void ln_rows(const float* __restrict__ in, const float* __restrict__ w,
                        const float* __restrict__ b, unsigned short* __restrict__ out) {
  int lane = threadIdx.x & 63;
  int row = blockIdx.x * 4 + (threadIdx.x >> 6);
  const float* p = in + (size_t)row * 768;
  float4 v[3];
  float s = 0.f, s2 = 0.f;
#pragma unroll
  for (int j = 0; j < 3; ++j) {
    v[j] = *(const float4*)(p + j * 256 + lane * 4);
    s  += v[j].x + v[j].y + v[j].z + v[j].w;
    s2 += v[j].x * v[j].x + v[j].y * v[j].y + v[j].z * v[j].z + v[j].w * v[j].w;
  }
#pragma unroll
  for (int o = 32; o >= 1; o >>= 1) { s += __shfl_xor(s, o); s2 += __shfl_xor(s2, o); }
  float mu = s * (1.f / 768.f);
  float var = s2 * (1.f / 768.f) - mu * mu;
  float rs = rsqrtf(var + 1e-6f);
#pragma unroll
  for (int j = 0; j < 3; ++j) {
    int c = j * 256 + lane * 4;
    float4 wv = *(const float4*)(w + c);
    float4 bv = *(const float4*)(b + c);
    ushort4 o4;
    o4.x = f2bf((v[j].x - mu) * rs * wv.x + bv.x);
    o4.y = f2bf((v[j].y - mu) * rs * wv.y + bv.y);
    o4.z = f2bf((v[j].z - mu) * rs * wv.z + bv.z);
    o4.w = f2bf((v[j].w - mu) * rs * wv.w + bv.w);
    *(ushort4*)(out + (size_t)row * 768 + c) = o4;
  }
}

// -------- GEMM 128x128, T3 2-phase double-buffered staging, LINEAR block map --------
// (R7 post-mortem: row-chunked XCD swizzle thrashed per-XCD L2 on the 4.7MB FC1
//  B-panel; default row-synchronous dispatch has better locality. Reverted.)
// C = A[M,K]*BT[N,K]^T + bias.  Per K-step: issue stage(t+1) -> buf^1, ds_read+MFMA
// on buf, then ONE vmcnt(0)+s_barrier (publish).
// EP 0: QKV scatter  1: Oproj(*lam1+resid->f32)  2: FC1+GELU->bf16  3: FC2(*lam2+hidden2->f32)
template <int EP>
__global__ void gemm_bf16(const unsigned short* __restrict__ A,
                          const unsigned short* __restrict__ BT,
                          const float* __restrict__ bias,
                          int N, int K,
                          void* __restrict__ out,
                          const float* __restrict__ scale,
                          const float* __restrict__ addv,
                          unsigned short* __restrict__ q_out,
                          unsigned short* __restrict__ k_out,
                          unsigned short* __restrict__ vt_out) {
  __shared__ unsigned short As[2][128 * 32];
  __shared__ unsigned short Bs[2][128 * 32];
  const int wid = threadIdx.x >> 6, lane = threadIdx.x & 63;
  const int bm = blockIdx.y * 128, bn = blockIdx.x * 128;
  const int wr = wid >> 1, wc = wid & 1;
  const int NT = K >> 5;

  auto stage = [&](int t, int buf) {
    int k0 = t << 5;
#pragma unroll
    for (int j = 0; j < 2; ++j) {
      int seg = wid * 2 + j;                 // 0..7, wave-uniform
      int row = seg * 16 + (lane >> 2);      // tile row 0..127
      int kc = k0 + (lane & 3) * 8;          // 8 bf16 = 16B per lane
      gld_lds16(A  + (size_t)(bm + row) * K + kc, (char*)As[buf] + seg * 1024);
      gld_lds16(BT + (size_t)(bn + row) * K + kc, (char*)Bs[buf] + seg * 1024);
    }
  };

  f32x4 acc[4][4] = {};

  // prologue: stage tile 0, publish
  stage(0, 0);
  asm volatile("s_waitcnt vmcnt(0)" ::: "memory");
  __builtin_amdgcn_sched_barrier(0);
  __builtin_amdgcn_s_barrier();
  __builtin_amdgcn_sched_barrier(0);

  for (int t = 0; t < NT; ++t) {
    if (t + 1 < NT) stage(t + 1, (t + 1) & 1);   // overlap with compute below
    const unsigned short* Ab = As[t & 1];
    const unsigned short* Bb = Bs[t & 1];
    bf16x8 af[4], bfr[4];
#pragma unroll
    for (int i = 0; i < 4; ++i)
      af[i] = *(const bf16x8*)(Ab + (wr * 64 + i * 16 + (lane & 15)) * 32 + (lane >> 4) * 8);
#pragma unroll
    for (int i = 0; i < 4; ++i)
      bfr[i] = *(const bf16x8*)(Bb + (wc * 64 + i * 16 + (lane & 15)) * 32 + (lane >> 4) * 8);
#pragma unroll
    for (int mi = 0; mi < 4; ++mi)
#pragma unroll
      for (int ni = 0; ni < 4; ++ni)
        acc[mi][ni] = __builtin_amdgcn_mfma_f32_16x16x32_bf16(af[mi], bfr[ni], acc[mi][ni], 0, 0, 0);
    // publish stage(t+1): drain own loads (they had the compute window to land),
    // then one barrier. Reads of buf[t&1] completed before MFMA (lgkmcnt), so
    // next iter's overwrite of buf[t&1] (tile t+2) is safe after this barrier.
    asm volatile("s_waitcnt vmcnt(0)" ::: "memory");
    __builtin_amdgcn_sched_barrier(0);
    __builtin_amdgcn_s_barrier();
    __builtin_amdgcn_sched_barrier(0);
  }

#pragma unroll
  for (int mi = 0; mi < 4; ++mi) {
#pragma unroll
    for (int ni = 0; ni < 4; ++ni) {
      int col = bn + wc * 64 + ni * 16 + (lane & 15);
      float bcol = bias[col];
#pragma unroll
      for (int r = 0; r < 4; ++r) {
        int row = bm + wr * 64 + mi * 16 + (lane >> 4) * 4 + r;
        float v = acc[mi][ni][r] + bcol;
        if (EP == 0) {
          int b = row >> 10, s = row & 1023;
          int piece = col / 768;
          int rc = col - piece * 768;
          int h = rc >> 6, d = rc & 63;
          unsigned short bvv = f2bf(v);
          if (piece == 0)      q_out [((size_t)(b * 12 + h) * 1024 + s) * 64 + d] = bvv;
          else if (piece == 1) k_out [((size_t)(b * 12 + h) * 1024 + s) * 64 + d] = bvv;
          else                 vt_out[((size_t)(b * 12 + h) * 64 + d) * 1024 + s] = bvv;
        } else if (EP == 1) {
          ((float*)out)[(size_t)row * 768 + col] = v * scale[col] + addv[(size_t)row * 768 + col];
        } else if (EP == 2) {
          float g = 0.5f * v * (1.f + erff(v * 0.70710678118654752f));
          ((unsigned short*)out)[(size_t)row * (size_t)N + col] = f2bf(g);
        } else {
          ((float*)out)[(size_t)row * 768 + col] = v * scale[col] + addv[(size_t)row * 768 + col];
        }
      }
    }
  }
}

// -------- flash attention v3 (unchanged): 4 waves x QBLK=32, KVBLK=64, --------
// 32x32x16 MFMA, swapped QK^T, in-register softmax, P->A-frag via cvt_pk+shfl,
// l-sum via ones-MFMA, defer-max, async-staged dbuf K/V.
__global__ __launch_bounds__(256) void attn_fwd(const unsigned short* __restrict__ qb,
                         const unsigned short* __restrict__ kb,
                         const unsigned short* __restrict__ vtb,
                         unsigned short* __restrict__ ctx) {
  __shared__ unsigned short Ks[2][64 * 64];   // [kv][d], XOR-swizzled rows
  __shared__ unsigned short VTs[2][64 * 64];  // [d][kv], XOR-swizzled rows
  __shared__ float alphaW[4][32];
  const int tid = threadIdx.x;
  const int wid = tid >> 6, lane = tid & 63;
  const int l31 = lane & 31;
  const bool hi = lane >= 32;
  const int hi8 = hi ? 8 : 0, hi16 = hi ? 16 : 0;
  const int sw0 = (l31 & 7) << 4;
  const int wg = (blockIdx.x & 7) * 96 + (blockIdx.x >> 3);
  const int bh = wg >> 3, qt = wg & 7;
  const int b = bh / 12, h = bh % 12;
  const unsigned short* qh  = qb  + (size_t)bh * 1024 * 64;
  const unsigned short* kh  = kb  + (size_t)bh * 1024 * 64;
  const unsigned short* vth = vtb + (size_t)bh * 64 * 1024;

  const int qrow = qt * 128 + wid * 32 + l31;
  bf16x8 qf[4];
#pragma unroll
  for (int kf = 0; kf < 4; ++kf)
    qf[kf] = *(const bf16x8*)(qh + (size_t)qrow * 64 + kf * 16 + hi8);

  bf16x8 ones;
#pragma unroll
  for (int i = 0; i < 8; ++i) ones[i] = (short)0x3F80;

  f32x16 o0 = {}, o1 = {}, l_acc = {};
  float mcol = -1e30f;
  const float sc = 0.125f * 1.44269504088896f;   // log2(e)/sqrt(D)

  const int r1 = tid >> 3;               // 0..31
  const int sl = tid & 7;
  const int cb = (sl * 16) ^ ((r1 & 7) << 4);

  {
    uint4 k0v = *(const uint4*)(kh + (size_t)r1 * 64 + sl * 8);
    uint4 k1v = *(const uint4*)(kh + (size_t)(r1 + 32) * 64 + sl * 8);
    uint4 v0v = *(const uint4*)(vth + (size_t)r1 * 1024 + sl * 8);
    uint4 v1v = *(const uint4*)(vth + (size_t)(r1 + 32) * 1024 + sl * 8);
    *(uint4*)((char*)Ks[0]  + r1 * 128 + cb) = k0v;
    *(uint4*)((char*)Ks[0]  + (r1 + 32) * 128 + cb) = k1v;
    *(uint4*)((char*)VTs[0] + r1 * 128 + cb) = v0v;
    *(uint4*)((char*)VTs[0] + (r1 + 32) * 128 + cb) = v1v;
  }

  uint4 kA, kB, vA, vB;
  for (int t = 0; t < 16; ++t) {
    if (t < 15) {
      const int s1 = (t + 1) * 64;
      kA = *(const uint4*)(kh + (size_t)(s1 + r1) * 64 + sl * 8);
      kB = *(const uint4*)(kh + (size_t)(s1 + r1 + 32) * 64 + sl * 8);
      vA = *(const uint4*)(vth + (size_t)r1 * 1024 + s1 + sl * 8);
      vB = *(const uint4*)(vth + (size_t)(r1 + 32) * 1024 + s1 + sl * 8);
    }
    asm volatile("s_waitcnt lgkmcnt(0)" ::: "memory");
    __builtin_amdgcn_s_barrier();
    const char* KsB  = (const char*)Ks[t & 1];
    const char* VTsB = (const char*)VTs[t & 1];

    f32x16 s0 = {}, s1v = {};
#pragma unroll
    for (int kf = 0; kf < 4; ++kf) {
      bf16x8 k0 = *(const bf16x8*)(KsB + l31 * 128 + ((kf * 32 + hi16) ^ sw0));
      bf16x8 k1 = *(const bf16x8*)(KsB + (l31 + 32) * 128 + ((kf * 32 + hi16) ^ sw0));
      s0  = __builtin_amdgcn_mfma_f32_32x32x16_bf16(k0, qf[kf], s0, 0, 0, 0);
      s1v = __builtin_amdgcn_mfma_f32_32x32x16_bf16(k1, qf[kf], s1v, 0, 0, 0);
    }

    float mt = s0[0];
#pragma unroll
    for (int i = 1; i < 16; ++i) mt = fmaxf(mt, s0[i]);
#pragma unroll
    for (int i = 0; i < 16; ++i) mt = fmaxf(mt, s1v[i]);
    mt *= sc;
    mt = fmaxf(mt, __shfl_xor(mt, 32));

    if (__ballot(mt > mcol + 8.f)) {
      float mnew = fmaxf(mcol, mt);
      float a = exp2f(mcol - mnew);
      if (lane < 32) alphaW[wid][lane] = a;
      mcol = mnew;
      asm volatile("s_waitcnt lgkmcnt(0)" ::: "memory");
      __builtin_amdgcn_sched_barrier(0);
#pragma unroll
      for (int r = 0; r < 16; ++r) {
        float av = alphaW[wid][(r & 3) + ((r >> 2) << 3) + (hi ? 4 : 0)];
        o0[r] *= av; o1[r] *= av; l_acc[r] *= av;
      }
    }

    float p0[16], p1[16];
#pragma unroll
    for (int i = 0; i < 16; ++i) p0[i] = exp2f(s0[i] * sc - mcol);
#pragma unroll
    for (int i = 0; i < 16; ++i) p1[i] = exp2f(s1v[i] * sc - mcol);
    uint32_t W[16], X[16];
#pragma unroll
    for (int i = 0; i < 8; ++i) {
      W[i]     = pkbf(p0[2 * i], p0[2 * i + 1]);
      W[8 + i] = pkbf(p1[2 * i], p1[2 * i + 1]);
    }
#pragma unroll
    for (int i = 0; i < 16; ++i) X[i] = (uint32_t)__shfl_xor((int)W[i], 32);
    bf16x8 pa[4];
    {
      union U4 { uint32_t u[4]; bf16x8 v; } f;
      f.u[0] = hi ? X[2] : W[0];  f.u[1] = hi ? X[3] : W[1];
      f.u[2] = hi ? W[2] : X[0];  f.u[3] = hi ? W[3] : X[1];   pa[0] = f.v;
      f.u[0] = hi ? X[6] : W[4];  f.u[1] = hi ? X[7] : W[5];
      f.u[2] = hi ? W[6] : X[4];  f.u[3] = hi ? W[7] : X[5];   pa[1] = f.v;
      f.u[0] = hi ? X[10] : W[8]; f.u[1] = hi ? X[11] : W[9];
      f.u[2] = hi ? W[10] : X[8]; f.u[3] = hi ? W[11] : X[9];  pa[2] = f.v;
      f.u[0] = hi ? X[14] : W[12]; f.u[1] = hi ? X[15] : W[13];
      f.u[2] = hi ? W[14] : X[12]; f.u[3] = hi ? W[15] : X[13]; pa[3] = f.v;
    }

#pragma unroll
    for (int f = 0; f < 4; ++f) {
      l_acc = __builtin_amdgcn_mfma_f32_32x32x16_bf16(pa[f], ones, l_acc, 0, 0, 0);
      bf16x8 v0 = *(const bf16x8*)(VTsB + l31 * 128 + ((f * 32 + hi16) ^ sw0));
      bf16x8 v1 = *(const bf16x8*)(VTsB + (l31 + 32) * 128 + ((f * 32 + hi16) ^ sw0));
      o0 = __builtin_amdgcn_mfma_f32_32x32x16_bf16(pa[f], v0, o0, 0, 0, 0);
      o1 = __builtin_amdgcn_mfma_f32_32x32x16_bf16(pa[f], v1, o1, 0, 0, 0);
    }

    if (t < 15) {
      asm volatile("s_waitcnt vmcnt(0)" ::: "memory");
      __builtin_amdgcn_sched_barrier(0);
      char* Kn = (char*)Ks[(t + 1) & 1];
      char* Vn = (char*)VTs[(t + 1) & 1];
      *(uint4*)(Kn + r1 * 128 + cb) = kA;
      *(uint4*)(Kn + (r1 + 32) * 128 + cb) = kB;
      *(uint4*)(Vn + r1 * 128 + cb) = vA;
      *(uint4*)(Vn + (r1 + 32) * 128 + cb) = vB;
    }
  }

#pragma unroll
  for (int r = 0; r < 16; ++r) {
    int rq = (r & 3) + ((r >> 2) << 3) + (hi ? 4 : 0);
    int srow = qt * 128 + wid * 32 + rq;
    float inv = 1.f / l_acc[r];
    size_t base = ((size_t)(b * 1024 + srow)) * 768 + h * 64;
    ctx[base + l31]      = f2bf(o0[r] * inv);
    ctx[base + 32 + l31] = f2bf(o1[r] * inv);
  }
}

extern "C" void kernel_launch(void* const* d_in, const int* in_sizes, int n_in,
                              void* d_out, int out_size, void* d_ws, size_t ws_size,
                              hipStream_t stream) {
  const float* hs    = (const float*)d_in[0];
  const float* ln1_w = (const float*)d_in[1];
  const float* ln1_b = (const float*)d_in[2];
  const float* q_w   = (const float*)d_in[3];
  const float* q_b   = (const float*)d_in[4];
  const float* k_w   = (const float*)d_in[5];
  const float* k_b   = (const float*)d_in[6];
  const float* v_w   = (const float*)d_in[7];
  const float* v_b   = (const float*)d_in[8];
  const float* o_w   = (const float*)d_in[9];
  const float* o_b   = (const float*)d_in[10];
  const float* lam1  = (const float*)d_in[11];
  const float* ln2_w = (const float*)d_in[12];
  const float* ln2_b = (const float*)d_in[13];
  const float* fc1_w = (const float*)d_in[14];
  const float* fc1_b = (const float*)d_in[15];
  const float* fc2_w = (const float*)d_in[16];
  const float* fc2_b = (const float*)d_in[17];
  const float* lam2  = (const float*)d_in[18];

  char* ws = (char*)d_ws;
  size_t off = 0;
  auto carve = [&](size_t bytes) { char* p = ws + off; off += (bytes + 255) & ~(size_t)255; return p; };
  unsigned short* wqkv_t = (unsigned short*)carve((size_t)2304 * 768 * 2);
  unsigned short* wo_t   = (unsigned short*)carve((size_t)768 * 768 * 2);
  unsigned short* wfc1_t = (unsigned short*)carve((size_t)3072 * 768 * 2);
  unsigned short* wfc2_t = (unsigned short*)carve((size_t)768 * 3072 * 2);
  float*          bqkv   = (float*)carve(2304 * 4);
  const size_t SB = (size_t)8192 * 768 * 2;              // one bf16 [8192][768] buffer
  char* unionA = carve(4 * SB);                          // x_ln|q|k|vt, later reused as act
  unsigned short* x_ln   = (unsigned short*)unionA;
  unsigned short* q_buf  = (unsigned short*)(unionA + SB);
  unsigned short* k_buf  = (unsigned short*)(unionA + 2 * SB);
  unsigned short* vt_buf = (unsigned short*)(unionA + 3 * SB);
  unsigned short* act    = (unsigned short*)unionA;      // FC1 out (x/q/k/vt dead by then)
  unsigned short* ctx    = (unsigned short*)carve(SB);
  float*          hidden2= (float*)carve((size_t)8192 * 768 * 4);
  unsigned short* y_ln   = (unsigned short*)carve(SB);

  pack_bias<<<dim3(9), dim3(256), 0, stream>>>(q_b, k_b, v_b, bqkv);
  transpose_w<<<dim3(12, 12), dim3(256), 0, stream>>>(q_w, wqkv_t, 768, 768);
  transpose_w<<<dim3(12, 12), dim3(256), 0, stream>>>(k_w, wqkv_t + (size_t)768 * 768, 768, 768);
  transpose_w<<<dim3(12, 12), dim3(256), 0, stream>>>(v_w, wqkv_t + (size_t)2 * 768 * 768, 768, 768);
  transpose_w<<<dim3(12, 12), dim3(256), 0, stream>>>(o_w, wo_t, 768, 768);
  transpose_w<<<dim3(48, 12), dim3(256), 0, stream>>>(fc1_w, wfc1_t, 768, 3072);
  transpose_w<<<dim3(12, 48), dim3(256), 0, stream>>>(fc2_w, wfc2_t, 3072, 768);

  ln_rows<<<dim3(2048), dim3(256), 0, stream>>>(hs, ln1_w, ln1_b, x_ln);
  gemm_bf16<0><<<dim3(18, 64), dim3(256), 0, stream>>>(x_ln, wqkv_t, bqkv, 2304, 768,
      nullptr, nullptr, nullptr, q_buf, k_buf, vt_buf);
  attn_fwd<<<dim3(768), dim3(256), 0, stream>>>(q_buf, k_buf, vt_buf, ctx);
  gemm_bf16<1><<<dim3(6, 64), dim3(256), 0, stream>>>(ctx, wo_t, o_b, 768, 768,
      hidden2, lam1, hs, nullptr, nullptr, nullptr);
  ln_rows<<<dim3(2048), dim3(256), 0, stream>>>(hidden2, ln2_w, ln2_b, y_ln);
  gemm_bf16<2><<<dim3(24, 64), dim3(256), 0, stream>>>(y_ln, wfc1_t, fc1_b, 3072, 768,
      act, nullptr, nullptr, nullptr, nullptr, nullptr);
  gemm_bf16<3><<<dim3(6, 64), dim3(256), 0, stream>>>(act, wfc2_t, fc2_b, 768, 3072,
      d_out, lam2, hidden2, nullptr, nullptr, nullptr);
}

// Round 9
// 414.533 us; speedup vs baseline: 1.0281x; 1.0281x over previous
//
#include <hip/hip_runtime.h>
#include <hip/hip_bf16.h>
#include <stdint.h>
#include <stddef.h>

using bf16x8 = __attribute__((ext_vector_type(8))) short;
using f32x4  = __attribute__((ext_vector_type(4))) float;
using f32x16 = __attribute__((ext_vector_type(16))) float;

#define DEV static __device__ __forceinline__

DEV unsigned short f2bf(float f) {
  union { float f; uint32_t u; } x; x.f = f;
  uint32_t u = x.u;
  u += 0x7fffu + ((u >> 16) & 1u);   // RNE
  return (unsigned short)(u >> 16);
}

DEV uint32_t pkbf(float a, float b) {   // packs to [b:a] (lo=a) -> v_cvt_pk_bf16_f32
  __hip_bfloat162 t = __float22bfloat162_rn(float2{a, b});
  union { __hip_bfloat162 h; uint32_t u; } c; c.h = t; return c.u;
}

DEV void gld_lds16(const void* g, void* lds) {
  __builtin_amdgcn_global_load_lds(
      (__attribute__((address_space(1))) void*)(uintptr_t)g,
      (__attribute__((address_space(3))) void*)(uintptr_t)lds, 16, 0, 0);
}

// -------- weight transpose: fp32 [K][N] -> bf16 [N][K] --------
__global__ void transpose_w(const float* __restrict__ in, unsigned short* __restrict__ out,
                            int K, int N) {
  __shared__ float tile[64][65];
  int n0 = blockIdx.x * 64, k0 = blockIdx.y * 64;
  int tx = threadIdx.x & 15, ty = threadIdx.x >> 4;
#pragma unroll
  for (int j = 0; j < 4; ++j) {
    int r = ty + j * 16;
    float4 v = *(const float4*)(in + (size_t)(k0 + r) * N + n0 + tx * 4);
    tile[r][tx * 4 + 0] = v.x; tile[r][tx * 4 + 1] = v.y;
    tile[r][tx * 4 + 2] = v.z; tile[r][tx * 4 + 3] = v.w;
  }
  __syncthreads();
#pragma unroll
  for (int j = 0; j < 4; ++j) {
    int n = ty + j * 16;
    ushort4 o;
    o.x = f2bf(tile[tx * 4 + 0][n]);
    o.y = f2bf(tile[tx * 4 + 1][n]);
    o.z = f2bf(tile[tx * 4 + 2][n]);
    o.w = f2bf(tile[tx * 4 + 3][n]);
    *(ushort4*)(out + (size_t)(n0 + n) * K + k0 + tx * 4) = o;
  }
}

// -------- V transpose: [B,H,S,D] bf16 -> [B,H,D,S] bf16 (per-head 64x64 tiles) --------
__global__ void transpose_v(const unsigned short* __restrict__ v,
                            unsigned short* __restrict__ vt) {
  __shared__ unsigned short tile[64][72];   // 72: keeps [s][8k] 16B-aligned
  const int bh = blockIdx.y;                // 0..95
  const int s0 = blockIdx.x * 64;
  const unsigned short* src = v  + (size_t)bh * 1024 * 64;
  unsigned short* dst       = vt + (size_t)bh * 64 * 1024;
  const int tid = threadIdx.x;
#pragma unroll
  for (int j = 0; j < 2; ++j) {
    int idx = tid + j * 256;
    int s = idx >> 3, c = (idx & 7) * 8;
    *(uint4*)&tile[s][c] = *(const uint4*)(src + (size_t)(s0 + s) * 64 + c);
  }
  __syncthreads();
#pragma unroll
  for (int j = 0; j < 2; ++j) {
    int idx = tid + j * 256;
    int d = idx >> 3, sc = (idx & 7) * 8;
    uint32_t t0 = (uint32_t)tile[sc + 0][d] | ((uint32_t)tile[sc + 1][d] << 16);
    uint32_t t1 = (uint32_t)tile[sc + 2][d] | ((uint32_t)tile[sc + 3][d] << 16);
    uint32_t t2 = (uint32_t)tile[sc + 4][d] | ((uint32_t)tile[sc + 5][d] << 16);
    uint32_t t3 = (uint32_t)tile[sc + 6][d] | ((uint32_t)tile[sc + 7][d] << 16);
    uint4 o; o.x = t0; o.y = t1; o.z = t2; o.w = t3;
    *(uint4*)(dst + (size_t)d * 1024 + s0 + sc) = o;
  }
}

__global__ void pack_bias(const float* __restrict__ q, const float* __restrict__ k,
                          const float* __restrict__ v, float* __restrict__ out) {
  int i = blockIdx.x * 256 + threadIdx.x;   // 0..2303
  const float* s = (i < 768) ? q : ((i < 1536) ? k : v);
  int r = i; if (r >= 1536) r -= 1536; else if (r >= 768) r -= 768;
  out[i] = s[r];
}

// -------- LayerNorm: wave per row, fp32 in -> bf16 out --------
__global__ void ln_rows(const float* __restrict__ in, const float* __restrict__ w,
                        const float* __restrict__ b, unsigned short* __restrict__ out) {
  int lane = threadIdx.x & 63;
  int row = blockIdx.x * 4 + (threadIdx.x >> 6);
  const float* p = in + (size_t)row * 768;
  float4 v[3];
  float s = 0.f, s2 = 0.f;
#pragma unroll
  for (int j = 0; j < 3; ++j) {
    v[j] = *(const float4*)(p + j * 256 + lane * 4);
    s  += v[j].x + v[j].y + v[j].z + v[j].w;
    s2 += v[j].x * v[j].x + v[j].y * v[j].y + v[j].z * v[j].z + v[j].w * v[j].w;
  }
#pragma unroll
  for (int o = 32; o >= 1; o >>= 1) { s += __shfl_xor(s, o); s2 += __shfl_xor(s2, o); }
  float mu = s * (1.f / 768.f);
  float var = s2 * (1.f / 768.f) - mu * mu;
  float rs = rsqrtf(var + 1e-6f);
#pragma unroll
  for (int j = 0; j < 3; ++j) {
    int c = j * 256 + lane * 4;
    float4 wv = *(const float4*)(w + c);
    float4 bv = *(const float4*)(b + c);
    ushort4 o4;
    o4.x = f2bf((v[j].x - mu) * rs * wv.x + bv.x);
    o4.y = f2bf((v[j].y - mu) * rs * wv.y + bv.y);
    o4.z = f2bf((v[j].z - mu) * rs * wv.z + bv.z);
    o4.w = f2bf((v[j].w - mu) * rs * wv.w + bv.w);
    *(ushort4*)(out + (size_t)row * 768 + c) = o4;
  }
}

// -------- GEMM 128x128, 3-deep pipeline, counted vmcnt(4) (T4), linear block map --------
// Tiles t+1 AND t+2 in flight; per step drain only t+1 (vmcnt(4)), never 0 mid-loop.
// EP 0: QKV (V written coalesced [B,H,S,D])  1: Oproj(*lam1+resid->f32)
// EP 2: FC1+GELU->bf16  3: FC2(*lam2+hidden2->f32)
template <int EP>
__global__ void gemm_bf16(const unsigned short* __restrict__ A,
                          const unsigned short* __restrict__ BT,
                          const float* __restrict__ bias,
                          int N, int K,
                          void* __restrict__ out,
                          const float* __restrict__ scale,
                          const float* __restrict__ addv,
                          unsigned short* __restrict__ q_out,
                          unsigned short* __restrict__ k_out,
                          unsigned short* __restrict__ v_out) {
  __shared__ unsigned short As[3][128 * 32];
  __shared__ unsigned short Bs[3][128 * 32];
  const int wid = threadIdx.x >> 6, lane = threadIdx.x & 63;
  const int bm = blockIdx.y * 128, bn = blockIdx.x * 128;
  const int wr = wid >> 1, wc = wid & 1;
  const int NT = K >> 5;

  auto stage = [&](int t, int buf) {
    int k0 = t << 5;
#pragma unroll
    for (int j = 0; j < 2; ++j) {
      int seg = wid * 2 + j;                 // 0..7, wave-uniform
      int row = seg * 16 + (lane >> 2);      // tile row 0..127
      int kc = k0 + (lane & 3) * 8;          // 8 bf16 = 16B per lane
      gld_lds16(A  + (size_t)(bm + row) * K + kc, (char*)As[buf] + seg * 1024);
      gld_lds16(BT + (size_t)(bn + row) * K + kc, (char*)Bs[buf] + seg * 1024);
    }
  };

  f32x4 acc[4][4] = {};

  // prologue: tiles 0 and 1 in flight; drain only tile 0, publish
  stage(0, 0);
  if (NT > 1) {
    stage(1, 1);
    asm volatile("s_waitcnt vmcnt(4)" ::: "memory");
  } else {
    asm volatile("s_waitcnt vmcnt(0)" ::: "memory");
  }
  __builtin_amdgcn_sched_barrier(0);
  __builtin_amdgcn_s_barrier();
  __builtin_amdgcn_sched_barrier(0);

  for (int t = 0; t < NT; ++t) {
    if (t + 2 < NT) stage(t + 2, (t + 2) % 3);   // 2-step-deep prefetch
    const unsigned short* Ab = As[t % 3];
    const unsigned short* Bb = Bs[t % 3];
    bf16x8 af[4], bfr[4];
#pragma unroll
    for (int i = 0; i < 4; ++i)
      af[i] = *(const bf16x8*)(Ab + (wr * 64 + i * 16 + (lane & 15)) * 32 + (lane >> 4) * 8);
#pragma unroll
    for (int i = 0; i < 4; ++i)
      bfr[i] = *(const bf16x8*)(Bb + (wc * 64 + i * 16 + (lane & 15)) * 32 + (lane >> 4) * 8);
#pragma unroll
    for (int mi = 0; mi < 4; ++mi)
#pragma unroll
      for (int ni = 0; ni < 4; ++ni)
        acc[mi][ni] = __builtin_amdgcn_mfma_f32_16x16x32_bf16(af[mi], bfr[ni], acc[mi][ni], 0, 0, 0);
    // drain ONLY tile t+1 (4 own loads of t+2 stay in flight), publish via barrier
    if (t + 2 < NT)      { asm volatile("s_waitcnt vmcnt(4)" ::: "memory"); }
    else if (t + 1 < NT) { asm volatile("s_waitcnt vmcnt(0)" ::: "memory"); }
    __builtin_amdgcn_sched_barrier(0);
    __builtin_amdgcn_s_barrier();
    __builtin_amdgcn_sched_barrier(0);
  }

#pragma unroll
  for (int mi = 0; mi < 4; ++mi) {
#pragma unroll
    for (int ni = 0; ni < 4; ++ni) {
      int col = bn + wc * 64 + ni * 16 + (lane & 15);
      float bcol = bias[col];
#pragma unroll
      for (int r = 0; r < 4; ++r) {
        int row = bm + wr * 64 + mi * 16 + (lane >> 4) * 4 + r;
        float v = acc[mi][ni][r] + bcol;
        if (EP == 0) {
          int b = row >> 10, s = row & 1023;
          int piece = col / 768;
          int rc = col - piece * 768;
          int h = rc >> 6, d = rc & 63;
          unsigned short bvv = f2bf(v);
          size_t idx = ((size_t)(b * 12 + h) * 1024 + s) * 64 + d;   // coalesced for q,k,v
          if (piece == 0)      q_out[idx] = bvv;
          else if (piece == 1) k_out[idx] = bvv;
          else                 v_out[idx] = bvv;
        } else if (EP == 1) {
          ((float*)out)[(size_t)row * 768 + col] = v * scale[col] + addv[(size_t)row * 768 + col];
        } else if (EP == 2) {
          float g = 0.5f * v * (1.f + erff(v * 0.70710678118654752f));
          ((unsigned short*)out)[(size_t)row * (size_t)N + col] = f2bf(g);
        } else {
          ((float*)out)[(size_t)row * 768 + col] = v * scale[col] + addv[(size_t)row * 768 + col];
        }
      }
    }
  }
}

// -------- flash attention v3 (unchanged): 4 waves x QBLK=32, KVBLK=64, --------
// 32x32x16 MFMA, swapped QK^T, in-register softmax, P->A-frag via cvt_pk+shfl,
// l-sum via ones-MFMA, defer-max, async-staged dbuf K/V.
__global__ __launch_bounds__(256) void attn_fwd(const unsigned short* __restrict__ qb,
                         const unsigned short* __restrict__ kb,
                         const unsigned short* __restrict__ vtb,
                         unsigned short* __restrict__ ctx) {
  __shared__ unsigned short Ks[2][64 * 64];   // [kv][d], XOR-swizzled rows
  __shared__ unsigned short VTs[2][64 * 64];  // [d][kv], XOR-swizzled rows
  __shared__ float alphaW[4][32];
  const int tid = threadIdx.x;
  const int wid = tid >> 6, lane = tid & 63;
  const int l31 = lane & 31;
  const bool hi = lane >= 32;
  const int hi8 = hi ? 8 : 0, hi16 = hi ? 16 : 0;
  const int sw0 = (l31 & 7) << 4;
  const int wg = (blockIdx.x & 7) * 96 + (blockIdx.x >> 3);
  const int bh = wg >> 3, qt = wg & 7;
  const int b = bh / 12, h = bh % 12;
  const unsigned short* qh  = qb  + (size_t)bh * 1024 * 64;
  const unsigned short* kh  = kb  + (size_t)bh * 1024 * 64;
  const unsigned short* vth = vtb + (size_t)bh * 64 * 1024;

  const int qrow = qt * 128 + wid * 32 + l31;
  bf16x8 qf[4];
#pragma unroll
  for (int kf = 0; kf < 4; ++kf)
    qf[kf] = *(const bf16x8*)(qh + (size_t)qrow * 64 + kf * 16 + hi8);

  bf16x8 ones;
#pragma unroll
  for (int i = 0; i < 8; ++i) ones[i] = (short)0x3F80;

  f32x16 o0 = {}, o1 = {}, l_acc = {};
  float mcol = -1e30f;
  const float sc = 0.125f * 1.44269504088896f;   // log2(e)/sqrt(D)

  const int r1 = tid >> 3;               // 0..31
  const int sl = tid & 7;
  const int cb = (sl * 16) ^ ((r1 & 7) << 4);

  {
    uint4 k0v = *(const uint4*)(kh + (size_t)r1 * 64 + sl * 8);
    uint4 k1v = *(const uint4*)(kh + (size_t)(r1 + 32) * 64 + sl * 8);
    uint4 v0v = *(const uint4*)(vth + (size_t)r1 * 1024 + sl * 8);
    uint4 v1v = *(const uint4*)(vth + (size_t)(r1 + 32) * 1024 + sl * 8);
    *(uint4*)((char*)Ks[0]  + r1 * 128 + cb) = k0v;
    *(uint4*)((char*)Ks[0]  + (r1 + 32) * 128 + cb) = k1v;
    *(uint4*)((char*)VTs[0] + r1 * 128 + cb) = v0v;
    *(uint4*)((char*)VTs[0] + (r1 + 32) * 128 + cb) = v1v;
  }

  uint4 kA, kB, vA, vB;
  for (int t = 0; t < 16; ++t) {
    if (t < 15) {
      const int s1 = (t + 1) * 64;
      kA = *(const uint4*)(kh + (size_t)(s1 + r1) * 64 + sl * 8);
      kB = *(const uint4*)(kh + (size_t)(s1 + r1 + 32) * 64 + sl * 8);
      vA = *(const uint4*)(vth + (size_t)r1 * 1024 + s1 + sl * 8);
      vB = *(const uint4*)(vth + (size_t)(r1 + 32) * 1024 + s1 + sl * 8);
    }
    asm volatile("s_waitcnt lgkmcnt(0)" ::: "memory");
    __builtin_amdgcn_s_barrier();
    const char* KsB  = (const char*)Ks[t & 1];
    const char* VTsB = (const char*)VTs[t & 1];

    f32x16 s0 = {}, s1v = {};
#pragma unroll
    for (int kf = 0; kf < 4; ++kf) {
      bf16x8 k0 = *(const bf16x8*)(KsB + l31 * 128 + ((kf * 32 + hi16) ^ sw0));
      bf16x8 k1 = *(const bf16x8*)(KsB + (l31 + 32) * 128 + ((kf * 32 + hi16) ^ sw0));
      s0  = __builtin_amdgcn_mfma_f32_32x32x16_bf16(k0, qf[kf], s0, 0, 0, 0);
      s1v = __builtin_amdgcn_mfma_f32_32x32x16_bf16(k1, qf[kf], s1v, 0, 0, 0);
    }

    float mt = s0[0];
#pragma unroll
    for (int i = 1; i < 16; ++i) mt = fmaxf(mt, s0[i]);
#pragma unroll
    for (int i = 0; i < 16; ++i) mt = fmaxf(mt, s1v[i]);
    mt *= sc;
    mt = fmaxf(mt, __shfl_xor(mt, 32));

    if (__ballot(mt > mcol + 8.f)) {
      float mnew = fmaxf(mcol, mt);
      float a = exp2f(mcol - mnew);
      if (lane < 32) alphaW[wid][lane] = a;
      mcol = mnew;
      asm volatile("s_waitcnt lgkmcnt(0)" ::: "memory");
      __builtin_amdgcn_sched_barrier(0);
#pragma unroll
      for (int r = 0; r < 16; ++r) {
        float av = alphaW[wid][(r & 3) + ((r >> 2) << 3) + (hi ? 4 : 0)];
        o0[r] *= av; o1[r] *= av; l_acc[r] *= av;
      }
    }

    float p0[16], p1[16];
#pragma unroll
    for (int i = 0; i < 16; ++i) p0[i] = exp2f(s0[i] * sc - mcol);
#pragma unroll
    for (int i = 0; i < 16; ++i) p1[i] = exp2f(s1v[i] * sc - mcol);
    uint32_t W[16], X[16];
#pragma unroll
    for (int i = 0; i < 8; ++i) {
      W[i]     = pkbf(p0[2 * i], p0[2 * i + 1]);
      W[8 + i] = pkbf(p1[2 * i], p1[2 * i + 1]);
    }
#pragma unroll
    for (int i = 0; i < 16; ++i) X[i] = (uint32_t)__shfl_xor((int)W[i], 32);
    bf16x8 pa[4];
    {
      union U4 { uint32_t u[4]; bf16x8 v; } f;
      f.u[0] = hi ? X[2] : W[0];  f.u[1] = hi ? X[3] : W[1];
      f.u[2] = hi ? W[2] : X[0];  f.u[3] = hi ? W[3] : X[1];   pa[0] = f.v;
      f.u[0] = hi ? X[6] : W[4];  f.u[1] = hi ? X[7] : W[5];
      f.u[2] = hi ? W[6] : X[4];  f.u[3] = hi ? W[7] : X[5];   pa[1] = f.v;
      f.u[0] = hi ? X[10] : W[8]; f.u[1] = hi ? X[11] : W[9];
      f.u[2] = hi ? W[10] : X[8]; f.u[3] = hi ? W[11] : X[9];  pa[2] = f.v;
      f.u[0] = hi ? X[14] : W[12]; f.u[1] = hi ? X[15] : W[13];
      f.u[2] = hi ? W[14] : X[12]; f.u[3] = hi ? W[15] : X[13]; pa[3] = f.v;
    }

#pragma unroll
    for (int f = 0; f < 4; ++f) {
      l_acc = __builtin_amdgcn_mfma_f32_32x32x16_bf16(pa[f], ones, l_acc, 0, 0, 0);
      bf16x8 v0 = *(const bf16x8*)(VTsB + l31 * 128 + ((f * 32 + hi16) ^ sw0));
      bf16x8 v1 = *(const bf16x8*)(VTsB + (l31 + 32) * 128 + ((f * 32 + hi16) ^ sw0));
      o0 = __builtin_amdgcn_mfma_f32_32x32x16_bf16(pa[f], v0, o0, 0, 0, 0);
      o1 = __builtin_amdgcn_mfma_f32_32x32x16_bf16(pa[f], v1, o1, 0, 0, 0);
    }

    if (t < 15) {
      asm volatile("s_waitcnt vmcnt(0)" ::: "memory");
      __builtin_amdgcn_sched_barrier(0);
      char* Kn = (char*)Ks[(t + 1) & 1];
      char* Vn = (char*)VTs[(t + 1) & 1];
      *(uint4*)(Kn + r1 * 128 + cb) = kA;
      *(uint4*)(Kn + (r1 + 32) * 128 + cb) = kB;
      *(uint4*)(Vn + r1 * 128 + cb) = vA;
      *(uint4*)(Vn + (r1 + 32) * 128 + cb) = vB;
    }
  }

#pragma unroll
  for (int r = 0; r < 16; ++r) {
    int rq = (r & 3) + ((r >> 2) << 3) + (hi ? 4 : 0);
    int srow = qt * 128 + wid * 32 + rq;
    float inv = 1.f / l_acc[r];
    size_t base = ((size_t)(b * 1024 + srow)) * 768 + h * 64;
    ctx[base + l31]      = f2bf(o0[r] * inv);
    ctx[base + 32 + l31] = f2bf(o1[r] * inv);
  }
}

extern "C" void kernel_launch(void* const* d_in, const int* in_sizes, int n_in,
                              void* d_out, int out_size, void* d_ws, size_t ws_size,
                              hipStream_t stream) {
  const float* hs    = (const float*)d_in[0];
  const float* ln1_w = (const float*)d_in[1];
  const float* ln1_b = (const float*)d_in[2];
  const float* q_w   = (const float*)d_in[3];
  const float* q_b   = (const float*)d_in[4];
  const float* k_w   = (const float*)d_in[5];
  const float* k_b   = (const float*)d_in[6];
  const float* v_w   = (const float*)d_in[7];
  const float* v_b   = (const float*)d_in[8];
  const float* o_w   = (const float*)d_in[9];
  const float* o_b   = (const float*)d_in[10];
  const float* lam1  = (const float*)d_in[11];
  const float* ln2_w = (const float*)d_in[12];
  const float* ln2_b = (const float*)d_in[13];
  const float* fc1_w = (const float*)d_in[14];
  const float* fc1_b = (const float*)d_in[15];
  const float* fc2_w = (const float*)d_in[16];
  const float* fc2_b = (const float*)d_in[17];
  const float* lam2  = (const float*)d_in[18];

  char* ws = (char*)d_ws;
  size_t off = 0;
  auto carve = [&](size_t bytes) { char* p = ws + off; off += (bytes + 255) & ~(size_t)255; return p; };
  unsigned short* wqkv_t = (unsigned short*)carve((size_t)2304 * 768 * 2);
  unsigned short* wo_t   = (unsigned short*)carve((size_t)768 * 768 * 2);
  unsigned short* wfc1_t = (unsigned short*)carve((size_t)3072 * 768 * 2);
  unsigned short* wfc2_t = (unsigned short*)carve((size_t)768 * 3072 * 2);
  float*          bqkv   = (float*)carve(2304 * 4);
  const size_t SB = (size_t)8192 * 768 * 2;              // one bf16 [8192][768] buffer
  char* unionA = carve(4 * SB);                          // x_ln|q|k|vt, later reused as act
  unsigned short* x_ln   = (unsigned short*)unionA;
  unsigned short* q_buf  = (unsigned short*)(unionA + SB);
  unsigned short* k_buf  = (unsigned short*)(unionA + 2 * SB);
  unsigned short* vt_buf = (unsigned short*)(unionA + 3 * SB);
  unsigned short* act    = (unsigned short*)unionA;      // FC1 out (x/q/k/vt dead by then)
  unsigned short* ctx    = (unsigned short*)carve(SB);
  float*          hidden2= (float*)carve((size_t)8192 * 768 * 4);
  unsigned short* y_ln   = (unsigned short*)carve(SB);
  // V staged coalesced into hidden2's region (dead until O-proj writes it)
  unsigned short* v_buf  = (unsigned short*)hidden2;

  pack_bias<<<dim3(9), dim3(256), 0, stream>>>(q_b, k_b, v_b, bqkv);
  transpose_w<<<dim3(12, 12), dim3(256), 0, stream>>>(q_w, wqkv_t, 768, 768);
  transpose_w<<<dim3(12, 12), dim3(256), 0, stream>>>(k_w, wqkv_t + (size_t)768 * 768, 768, 768);
  transpose_w<<<dim3(12, 12), dim3(256), 0, stream>>>(v_w, wqkv_t + (size_t)2 * 768 * 768, 768, 768);
  transpose_w<<<dim3(12, 12), dim3(256), 0, stream>>>(o_w, wo_t, 768, 768);
  transpose_w<<<dim3(48, 12), dim3(256), 0, stream>>>(fc1_w, wfc1_t, 768, 3072);
  transpose_w<<<dim3(12, 48), dim3(256), 0, stream>>>(fc2_w, wfc2_t, 3072, 768);

  ln_rows<<<dim3(2048), dim3(256), 0, stream>>>(hs, ln1_w, ln1_b, x_ln);
  gemm_bf16<0><<<dim3(18, 64), dim3(256), 0, stream>>>(x_ln, wqkv_t, bqkv, 2304, 768,
      nullptr, nullptr, nullptr, q_buf, k_buf, v_buf);
  transpose_v<<<dim3(16, 96), dim3(256), 0, stream>>>(v_buf, vt_buf);
  attn_fwd<<<dim3(768), dim3(256), 0, stream>>>(q_buf, k_buf, vt_buf, ctx);
  gemm_bf16<1><<<dim3(6, 64), dim3(256), 0, stream>>>(ctx, wo_t, o_b, 768, 768,
      hidden2, lam1, hs, nullptr, nullptr, nullptr);
  ln_rows<<<dim3(2048), dim3(256), 0, stream>>>(hidden2, ln2_w, ln2_b, y_ln);
  gemm_bf16<2><<<dim3(24, 64), dim3(256), 0, stream>>>(y_ln, wfc1_t, fc1_b, 3072, 768,
      act, nullptr, nullptr, nullptr, nullptr, nullptr);
  gemm_bf16<3><<<dim3(6, 64), dim3(256), 0, stream>>>(act, wfc2_t, fc2_b, 768, 3072,
      d_out, lam2, hidden2, nullptr, nullptr, nullptr);
}

// Round 10
// 405.755 us; speedup vs baseline: 1.0504x; 1.0216x over previous
//
#include <hip/hip_runtime.h>
#include <hip/hip_bf16.h>
#include <stdint.h>
#include <stddef.h>

using bf16x8 = __attribute__((ext_vector_type(8))) short;
using f32x4  = __attribute__((ext_vector_type(4))) float;
using f32x16 = __attribute__((ext_vector_type(16))) float;

#define DEV static __device__ __forceinline__

DEV unsigned short f2bf(float f) {
  union { float f; uint32_t u; } x; x.f = f;
  uint32_t u = x.u;
  u += 0x7fffu + ((u >> 16) & 1u);   // RNE
  return (unsigned short)(u >> 16);
}

DEV uint32_t pkbf(float a, float b) {   // packs to [b:a] (lo=a) -> v_cvt_pk_bf16_f32
  __hip_bfloat162 t = __float22bfloat162_rn(float2{a, b});
  union { __hip_bfloat162 h; uint32_t u; } c; c.h = t; return c.u;
}

DEV void gld_lds16(const void* g, void* lds) {
  __builtin_amdgcn_global_load_lds(
      (__attribute__((address_space(1))) void*)(uintptr_t)g,
      (__attribute__((address_space(3))) void*)(uintptr_t)lds, 16, 0, 0);
}

// -------- fused preprocessing: 6 weight transposes (fp32 [K][N] -> bf16 [N][K])
// -------- + QKV bias pack, one launch.  flat block id ranges per weight.
__global__ void preprocess(const float* __restrict__ q_w, const float* __restrict__ k_w,
                           const float* __restrict__ v_w, const float* __restrict__ o_w,
                           const float* __restrict__ fc1_w, const float* __restrict__ fc2_w,
                           const float* __restrict__ q_b, const float* __restrict__ k_b,
                           const float* __restrict__ v_b,
                           unsigned short* __restrict__ wqkv_t, unsigned short* __restrict__ wo_t,
                           unsigned short* __restrict__ wfc1_t, unsigned short* __restrict__ wfc2_t,
                           float* __restrict__ bqkv) {
  const int blk = blockIdx.x;
  if (blk >= 1728) {                       // bias pack: blocks 1728..1736
    int i = (blk - 1728) * 256 + threadIdx.x;   // 0..2303
    const float* s = (i < 768) ? q_b : ((i < 1536) ? k_b : v_b);
    int r = i; if (r >= 1536) r -= 1536; else if (r >= 768) r -= 768;
    bqkv[i] = s[r];
    return;
  }
  const float* in; unsigned short* out; int K, N, nx, local;
  if (blk < 576) {                         // q,k,v,o: 144 tiles each (12x12)
    local = blk % 144; int wsel = blk / 144;
    K = 768; N = 768; nx = 12;
    in  = (wsel == 0) ? q_w : (wsel == 1) ? k_w : (wsel == 2) ? v_w : o_w;
    out = (wsel < 3) ? (wqkv_t + (size_t)wsel * 768 * 768) : wo_t;
  } else if (blk < 1152) {                 // fc1: 48x12
    local = blk - 576; K = 768; N = 3072; nx = 48; in = fc1_w; out = wfc1_t;
  } else {                                 // fc2: 12x48
    local = blk - 1152; K = 3072; N = 768; nx = 12; in = fc2_w; out = wfc2_t;
  }
  const int n0 = (local % nx) * 64, k0 = (local / nx) * 64;
  __shared__ float tile[64][65];
  const int tx = threadIdx.x & 15, ty = threadIdx.x >> 4;
#pragma unroll
  for (int j = 0; j < 4; ++j) {
    int r = ty + j * 16;
    float4 v = *(const float4*)(in + (size_t)(k0 + r) * N + n0 + tx * 4);
    tile[r][tx * 4 + 0] = v.x; tile[r][tx * 4 + 1] = v.y;
    tile[r][tx * 4 + 2] = v.z; tile[r][tx * 4 + 3] = v.w;
  }
  __syncthreads();
#pragma unroll
  for (int j = 0; j < 4; ++j) {
    int n = ty + j * 16;
    ushort4 o;
    o.x = f2bf(tile[tx * 4 + 0][n]);
    o.y = f2bf(tile[tx * 4 + 1][n]);
    o.z = f2bf(tile[tx * 4 + 2][n]);
    o.w = f2bf(tile[tx * 4 + 3][n]);
    *(ushort4*)(out + (size_t)(n0 + n) * K + k0 + tx * 4) = o;
  }
}

// -------- V transpose: [B,H,S,D] bf16 -> [B,H,D,S] bf16 (per-head 64x64 tiles) --------
__global__ void transpose_v(const unsigned short* __restrict__ v,
                            unsigned short* __restrict__ vt) {
  __shared__ unsigned short tile[64][72];   // 72: keeps [s][8k] 16B-aligned
  const int bh = blockIdx.y;                // 0..95
  const int s0 = blockIdx.x * 64;
  const unsigned short* src = v  + (size_t)bh * 1024 * 64;
  unsigned short* dst       = vt + (size_t)bh * 64 * 1024;
  const int tid = threadIdx.x;
#pragma unroll
  for (int j = 0; j < 2; ++j) {
    int idx = tid + j * 256;
    int s = idx >> 3, c = (idx & 7) * 8;
    *(uint4*)&tile[s][c] = *(const uint4*)(src + (size_t)(s0 + s) * 64 + c);
  }
  __syncthreads();
#pragma unroll
  for (int j = 0; j < 2; ++j) {
    int idx = tid + j * 256;
    int d = idx >> 3, sc = (idx & 7) * 8;
    uint32_t t0 = (uint32_t)tile[sc + 0][d] | ((uint32_t)tile[sc + 1][d] << 16);
    uint32_t t1 = (uint32_t)tile[sc + 2][d] | ((uint32_t)tile[sc + 3][d] << 16);
    uint32_t t2 = (uint32_t)tile[sc + 4][d] | ((uint32_t)tile[sc + 5][d] << 16);
    uint32_t t3 = (uint32_t)tile[sc + 6][d] | ((uint32_t)tile[sc + 7][d] << 16);
    uint4 o; o.x = t0; o.y = t1; o.z = t2; o.w = t3;
    *(uint4*)(dst + (size_t)d * 1024 + s0 + sc) = o;
  }
}

// -------- LayerNorm: wave per row, fp32 in -> bf16 out --------
__global__ void ln_rows(const float* __restrict__ in, const float* __restrict__ w,
                        const float* __restrict__ b, unsigned short* __restrict__ out) {
  int lane = threadIdx.x & 63;
  int row = blockIdx.x * 4 + (threadIdx.x >> 6);
  const float* p = in + (size_t)row * 768;
  float4 v[3];
  float s = 0.f, s2 = 0.f;
#pragma unroll
  for (int j = 0; j < 3; ++j) {
    v[j] = *(const float4*)(p + j * 256 + lane * 4);
    s  += v[j].x + v[j].y + v[j].z + v[j].w;
    s2 += v[j].x * v[j].x + v[j].y * v[j].y + v[j].z * v[j].z + v[j].w * v[j].w;
  }
#pragma unroll
  for (int o = 32; o >= 1; o >>= 1) { s += __shfl_xor(s, o); s2 += __shfl_xor(s2, o); }
  float mu = s * (1.f / 768.f);
  float var = s2 * (1.f / 768.f) - mu * mu;
  float rs = rsqrtf(var + 1e-6f);
#pragma unroll
  for (int j = 0; j < 3; ++j) {
    int c = j * 256 + lane * 4;
    float4 wv = *(const float4*)(w + c);
    float4 bv = *(const float4*)(b + c);
    ushort4 o4;
    o4.x = f2bf((v[j].x - mu) * rs * wv.x + bv.x);
    o4.y = f2bf((v[j].y - mu) * rs * wv.y + bv.y);
    o4.z = f2bf((v[j].z - mu) * rs * wv.z + bv.z);
    o4.w = f2bf((v[j].w - mu) * rs * wv.w + bv.w);
    *(ushort4*)(out + (size_t)row * 768 + c) = o4;
  }
}

// -------- GEMM 128x128, 3-deep counted-vmcnt pipeline + T2 LDS XOR-swizzle --------
// Swizzle (rule 21): linear global_load_lds dest + INVERSE-swizzled global source
// (kc = 8*((lane&3)^(localrow&3))) + swizzled frag read (col ^= ((row&3)*8 elems)).
// Kills the 4-way conflict of 8-lane groups on 64B-row tiles (4.7M -> ~0).
// EP 0: QKV (coalesced [B,H,S,D])  1: Oproj(*lam1+resid->f32)
// EP 2: FC1+GELU->bf16  3: FC2(*lam2+hidden2->f32)
template <int EP>
__global__ void gemm_bf16(const unsigned short* __restrict__ A,
                          const unsigned short* __restrict__ BT,
                          const float* __restrict__ bias,
                          int N, int K,
                          void* __restrict__ out,
                          const float* __restrict__ scale,
                          const float* __restrict__ addv,
                          unsigned short* __restrict__ q_out,
                          unsigned short* __restrict__ k_out,
                          unsigned short* __restrict__ v_out) {
  __shared__ unsigned short As[3][128 * 32];
  __shared__ unsigned short Bs[3][128 * 32];
  const int wid = threadIdx.x >> 6, lane = threadIdx.x & 63;
  const int bm = blockIdx.y * 128, bn = blockIdx.x * 128;
  const int wr = wid >> 1, wc = wid & 1;
  const int NT = K >> 5;

  // inverse-swizzled source column (elements): LDS slot (row, g) holds
  // global col 8*(g ^ (row&3))
  const int kcs = 8 * ((lane & 3) ^ ((lane >> 2) & 3));

  auto stage = [&](int t, int buf) {
    int k0 = t << 5;
#pragma unroll
    for (int j = 0; j < 2; ++j) {
      int seg = wid * 2 + j;                 // 0..7, wave-uniform
      int row = seg * 16 + (lane >> 2);      // tile row 0..127
      gld_lds16(A  + (size_t)(bm + row) * K + k0 + kcs, (char*)As[buf] + seg * 1024);
      gld_lds16(BT + (size_t)(bn + row) * K + k0 + kcs, (char*)Bs[buf] + seg * 1024);
    }
  };

  // swizzled fragment read column (elements): row&3 == lane&3 for all frag rows
  const int fcol = 8 * ((lane >> 4) ^ (lane & 3));

  f32x4 acc[4][4] = {};

  // prologue: tiles 0 and 1 in flight; drain only tile 0, publish
  stage(0, 0);
  if (NT > 1) {
    stage(1, 1);
    asm volatile("s_waitcnt vmcnt(4)" ::: "memory");
  } else {
    asm volatile("s_waitcnt vmcnt(0)" ::: "memory");
  }
  __builtin_amdgcn_sched_barrier(0);
  __builtin_amdgcn_s_barrier();
  __builtin_amdgcn_sched_barrier(0);

  for (int t = 0; t < NT; ++t) {
    if (t + 2 < NT) stage(t + 2, (t + 2) % 3);   // 2-step-deep prefetch
    const unsigned short* Ab = As[t % 3];
    const unsigned short* Bb = Bs[t % 3];
    bf16x8 af[4], bfr[4];
#pragma unroll
    for (int i = 0; i < 4; ++i)
      af[i] = *(const bf16x8*)(Ab + (wr * 64 + i * 16 + (lane & 15)) * 32 + fcol);
#pragma unroll
    for (int i = 0; i < 4; ++i)
      bfr[i] = *(const bf16x8*)(Bb + (wc * 64 + i * 16 + (lane & 15)) * 32 + fcol);
#pragma unroll
    for (int mi = 0; mi < 4; ++mi)
#pragma unroll
      for (int ni = 0; ni < 4; ++ni)
        acc[mi][ni] = __builtin_amdgcn_mfma_f32_16x16x32_bf16(af[mi], bfr[ni], acc[mi][ni], 0, 0, 0);
    // drain ONLY tile t+1 (4 own loads of t+2 stay in flight), publish via barrier
    if (t + 2 < NT)      { asm volatile("s_waitcnt vmcnt(4)" ::: "memory"); }
    else if (t + 1 < NT) { asm volatile("s_waitcnt vmcnt(0)" ::: "memory"); }
    __builtin_amdgcn_sched_barrier(0);
    __builtin_amdgcn_s_barrier();
    __builtin_amdgcn_sched_barrier(0);
  }

#pragma unroll
  for (int mi = 0; mi < 4; ++mi) {
#pragma unroll
    for (int ni = 0; ni < 4; ++ni) {
      int col = bn + wc * 64 + ni * 16 + (lane & 15);
      float bcol = bias[col];
#pragma unroll
      for (int r = 0; r < 4; ++r) {
        int row = bm + wr * 64 + mi * 16 + (lane >> 4) * 4 + r;
        float v = acc[mi][ni][r] + bcol;
        if (EP == 0) {
          int b = row >> 10, s = row & 1023;
          int piece = col / 768;
          int rc = col - piece * 768;
          int h = rc >> 6, d = rc & 63;
          unsigned short bvv = f2bf(v);
          size_t idx = ((size_t)(b * 12 + h) * 1024 + s) * 64 + d;   // coalesced for q,k,v
          if (piece == 0)      q_out[idx] = bvv;
          else if (piece == 1) k_out[idx] = bvv;
          else                 v_out[idx] = bvv;
        } else if (EP == 1) {
          ((float*)out)[(size_t)row * 768 + col] = v * scale[col] + addv[(size_t)row * 768 + col];
        } else if (EP == 2) {
          float g = 0.5f * v * (1.f + erff(v * 0.70710678118654752f));
          ((unsigned short*)out)[(size_t)row * (size_t)N + col] = f2bf(g);
        } else {
          ((float*)out)[(size_t)row * 768 + col] = v * scale[col] + addv[(size_t)row * 768 + col];
        }
      }
    }
  }
}

// -------- flash attention v3 (unchanged): 4 waves x QBLK=32, KVBLK=64, --------
// 32x32x16 MFMA, swapped QK^T, in-register softmax, P->A-frag via cvt_pk+shfl,
// l-sum via ones-MFMA, defer-max, async-staged dbuf K/V.
__global__ __launch_bounds__(256) void attn_fwd(const unsigned short* __restrict__ qb,
                         const unsigned short* __restrict__ kb,
                         const unsigned short* __restrict__ vtb,
                         unsigned short* __restrict__ ctx) {
  __shared__ unsigned short Ks[2][64 * 64];   // [kv][d], XOR-swizzled rows
  __shared__ unsigned short VTs[2][64 * 64];  // [d][kv], XOR-swizzled rows
  __shared__ float alphaW[4][32];
  const int tid = threadIdx.x;
  const int wid = tid >> 6, lane = tid & 63;
  const int l31 = lane & 31;
  const bool hi = lane >= 32;
  const int hi8 = hi ? 8 : 0, hi16 = hi ? 16 : 0;
  const int sw0 = (l31 & 7) << 4;
  const int wg = (blockIdx.x & 7) * 96 + (blockIdx.x >> 3);
  const int bh = wg >> 3, qt = wg & 7;
  const int b = bh / 12, h = bh % 12;
  const unsigned short* qh  = qb  + (size_t)bh * 1024 * 64;
  const unsigned short* kh  = kb  + (size_t)bh * 1024 * 64;
  const unsigned short* vth = vtb + (size_t)bh * 64 * 1024;

  const int qrow = qt * 128 + wid * 32 + l31;
  bf16x8 qf[4];
#pragma unroll
  for (int kf = 0; kf < 4; ++kf)
    qf[kf] = *(const bf16x8*)(qh + (size_t)qrow * 64 + kf * 16 + hi8);

  bf16x8 ones;
#pragma unroll
  for (int i = 0; i < 8; ++i) ones[i] = (short)0x3F80;

  f32x16 o0 = {}, o1 = {}, l_acc = {};
  float mcol = -1e30f;
  const float sc = 0.125f * 1.44269504088896f;   // log2(e)/sqrt(D)

  const int r1 = tid >> 3;               // 0..31
  const int sl = tid & 7;
  const int cb = (sl * 16) ^ ((r1 & 7) << 4);

  {
    uint4 k0v = *(const uint4*)(kh + (size_t)r1 * 64 + sl * 8);
    uint4 k1v = *(const uint4*)(kh + (size_t)(r1 + 32) * 64 + sl * 8);
    uint4 v0v = *(const uint4*)(vth + (size_t)r1 * 1024 + sl * 8);
    uint4 v1v = *(const uint4*)(vth + (size_t)(r1 + 32) * 1024 + sl * 8);
    *(uint4*)((char*)Ks[0]  + r1 * 128 + cb) = k0v;
    *(uint4*)((char*)Ks[0]  + (r1 + 32) * 128 + cb) = k1v;
    *(uint4*)((char*)VTs[0] + r1 * 128 + cb) = v0v;
    *(uint4*)((char*)VTs[0] + (r1 + 32) * 128 + cb) = v1v;
  }

  uint4 kA, kB, vA, vB;
  for (int t = 0; t < 16; ++t) {
    if (t < 15) {
      const int s1 = (t + 1) * 64;
      kA = *(const uint4*)(kh + (size_t)(s1 + r1) * 64 + sl * 8);
      kB = *(const uint4*)(kh + (size_t)(s1 + r1 + 32) * 64 + sl * 8);
      vA = *(const uint4*)(vth + (size_t)r1 * 1024 + s1 + sl * 8);
      vB = *(const uint4*)(vth + (size_t)(r1 + 32) * 1024 + s1 + sl * 8);
    }
    asm volatile("s_waitcnt lgkmcnt(0)" ::: "memory");
    __builtin_amdgcn_s_barrier();
    const char* KsB  = (const char*)Ks[t & 1];
    const char* VTsB = (const char*)VTs[t & 1];

    f32x16 s0 = {}, s1v = {};
#pragma unroll
    for (int kf = 0; kf < 4; ++kf) {
      bf16x8 k0 = *(const bf16x8*)(KsB + l31 * 128 + ((kf * 32 + hi16) ^ sw0));
      bf16x8 k1 = *(const bf16x8*)(KsB + (l31 + 32) * 128 + ((kf * 32 + hi16) ^ sw0));
      s0  = __builtin_amdgcn_mfma_f32_32x32x16_bf16(k0, qf[kf], s0, 0, 0, 0);
      s1v = __builtin_amdgcn_mfma_f32_32x32x16_bf16(k1, qf[kf], s1v, 0, 0, 0);
    }

    float mt = s0[0];
#pragma unroll
    for (int i = 1; i < 16; ++i) mt = fmaxf(mt, s0[i]);
#pragma unroll
    for (int i = 0; i < 16; ++i) mt = fmaxf(mt, s1v[i]);
    mt *= sc;
    mt = fmaxf(mt, __shfl_xor(mt, 32));

    if (__ballot(mt > mcol + 8.f)) {
      float mnew = fmaxf(mcol, mt);
      float a = exp2f(mcol - mnew);
      if (lane < 32) alphaW[wid][lane] = a;
      mcol = mnew;
      asm volatile("s_waitcnt lgkmcnt(0)" ::: "memory");
      __builtin_amdgcn_sched_barrier(0);
#pragma unroll
      for (int r = 0; r < 16; ++r) {
        float av = alphaW[wid][(r & 3) + ((r >> 2) << 3) + (hi ? 4 : 0)];
        o0[r] *= av; o1[r] *= av; l_acc[r] *= av;
      }
    }

    float p0[16], p1[16];
#pragma unroll
    for (int i = 0; i < 16; ++i) p0[i] = exp2f(s0[i] * sc - mcol);
#pragma unroll
    for (int i = 0; i < 16; ++i) p1[i] = exp2f(s1v[i] * sc - mcol);
    uint32_t W[16], X[16];
#pragma unroll
    for (int i = 0; i < 8; ++i) {
      W[i]     = pkbf(p0[2 * i], p0[2 * i + 1]);
      W[8 + i] = pkbf(p1[2 * i], p1[2 * i + 1]);
    }
#pragma unroll
    for (int i = 0; i < 16; ++i) X[i] = (uint32_t)__shfl_xor((int)W[i], 32);
    bf16x8 pa[4];
    {
      union U4 { uint32_t u[4]; bf16x8 v; } f;
      f.u[0] = hi ? X[2] : W[0];  f.u[1] = hi ? X[3] : W[1];
      f.u[2] = hi ? W[2] : X[0];  f.u[3] = hi ? W[3] : X[1];   pa[0] = f.v;
      f.u[0] = hi ? X[6] : W[4];  f.u[1] = hi ? X[7] : W[5];
      f.u[2] = hi ? W[6] : X[4];  f.u[3] = hi ? W[7] : X[5];   pa[1] = f.v;
      f.u[0] = hi ? X[10] : W[8]; f.u[1] = hi ? X[11] : W[9];
      f.u[2] = hi ? W[10] : X[8]; f.u[3] = hi ? W[11] : X[9];  pa[2] = f.v;
      f.u[0] = hi ? X[14] : W[12]; f.u[1] = hi ? X[15] : W[13];
      f.u[2] = hi ? W[14] : X[12]; f.u[3] = hi ? W[15] : X[13]; pa[3] = f.v;
    }

#pragma unroll
    for (int f = 0; f < 4; ++f) {
      l_acc = __builtin_amdgcn_mfma_f32_32x32x16_bf16(pa[f], ones, l_acc, 0, 0, 0);
      bf16x8 v0 = *(const bf16x8*)(VTsB + l31 * 128 + ((f * 32 + hi16) ^ sw0));
      bf16x8 v1 = *(const bf16x8*)(VTsB + (l31 + 32) * 128 + ((f * 32 + hi16) ^ sw0));
      o0 = __builtin_amdgcn_mfma_f32_32x32x16_bf16(pa[f], v0, o0, 0, 0, 0);
      o1 = __builtin_amdgcn_mfma_f32_32x32x16_bf16(pa[f], v1, o1, 0, 0, 0);
    }

    if (t < 15) {
      asm volatile("s_waitcnt vmcnt(0)" ::: "memory");
      __builtin_amdgcn_sched_barrier(0);
      char* Kn = (char*)Ks[(t + 1) & 1];
      char* Vn = (char*)VTs[(t + 1) & 1];
      *(uint4*)(Kn + r1 * 128 + cb) = kA;
      *(uint4*)(Kn + (r1 + 32) * 128 + cb) = kB;
      *(uint4*)(Vn + r1 * 128 + cb) = vA;
      *(uint4*)(Vn + (r1 + 32) * 128 + cb) = vB;
    }
  }

#pragma unroll
  for (int r = 0; r < 16; ++r) {
    int rq = (r & 3) + ((r >> 2) << 3) + (hi ? 4 : 0);
    int srow = qt * 128 + wid * 32 + rq;
    float inv = 1.f / l_acc[r];
    size_t base = ((size_t)(b * 1024 + srow)) * 768 + h * 64;
    ctx[base + l31]      = f2bf(o0[r] * inv);
    ctx[base + 32 + l31] = f2bf(o1[r] * inv);
  }
}

extern "C" void kernel_launch(void* const* d_in, const int* in_sizes, int n_in,
                              void* d_out, int out_size, void* d_ws, size_t ws_size,
                              hipStream_t stream) {
  const float* hs    = (const float*)d_in[0];
  const float* ln1_w = (const float*)d_in[1];
  const float* ln1_b = (const float*)d_in[2];
  const float* q_w   = (const float*)d_in[3];
  const float* q_b   = (const float*)d_in[4];
  const float* k_w   = (const float*)d_in[5];
  const float* k_b   = (const float*)d_in[6];
  const float* v_w   = (const float*)d_in[7];
  const float* v_b   = (const float*)d_in[8];
  const float* o_w   = (const float*)d_in[9];
  const float* o_b   = (const float*)d_in[10];
  const float* lam1  = (const float*)d_in[11];
  const float* ln2_w = (const float*)d_in[12];
  const float* ln2_b = (const float*)d_in[13];
  const float* fc1_w = (const float*)d_in[14];
  const float* fc1_b = (const float*)d_in[15];
  const float* fc2_w = (const float*)d_in[16];
  const float* fc2_b = (const float*)d_in[17];
  const float* lam2  = (const float*)d_in[18];

  char* ws = (char*)d_ws;
  size_t off = 0;
  auto carve = [&](size_t bytes) { char* p = ws + off; off += (bytes + 255) & ~(size_t)255; return p; };
  unsigned short* wqkv_t = (unsigned short*)carve((size_t)2304 * 768 * 2);
  unsigned short* wo_t   = (unsigned short*)carve((size_t)768 * 768 * 2);
  unsigned short* wfc1_t = (unsigned short*)carve((size_t)3072 * 768 * 2);
  unsigned short* wfc2_t = (unsigned short*)carve((size_t)768 * 3072 * 2);
  float*          bqkv   = (float*)carve(2304 * 4);
  const size_t SB = (size_t)8192 * 768 * 2;              // one bf16 [8192][768] buffer
  char* unionA = carve(4 * SB);                          // x_ln|q|k|vt, later reused as act
  unsigned short* x_ln   = (unsigned short*)unionA;
  unsigned short* q_buf  = (unsigned short*)(unionA + SB);
  unsigned short* k_buf  = (unsigned short*)(unionA + 2 * SB);
  unsigned short* vt_buf = (unsigned short*)(unionA + 3 * SB);
  unsigned short* act    = (unsigned short*)unionA;      // FC1 out (x/q/k/vt dead by then)
  unsigned short* ctx    = (unsigned short*)carve(SB);
  float*          hidden2= (float*)carve((size_t)8192 * 768 * 4);
  unsigned short* y_ln   = (unsigned short*)carve(SB);
  // V staged coalesced into hidden2's region (dead until O-proj writes it)
  unsigned short* v_buf  = (unsigned short*)hidden2;

  preprocess<<<dim3(1737), dim3(256), 0, stream>>>(q_w, k_w, v_w, o_w, fc1_w, fc2_w,
      q_b, k_b, v_b, wqkv_t, wo_t, wfc1_t, wfc2_t, bqkv);

  ln_rows<<<dim3(2048), dim3(256), 0, stream>>>(hs, ln1_w, ln1_b, x_ln);
  gemm_bf16<0><<<dim3(18, 64), dim3(256), 0, stream>>>(x_ln, wqkv_t, bqkv, 2304, 768,
      nullptr, nullptr, nullptr, q_buf, k_buf, v_buf);
  transpose_v<<<dim3(16, 96), dim3(256), 0, stream>>>(v_buf, vt_buf);
  attn_fwd<<<dim3(768), dim3(256), 0, stream>>>(q_buf, k_buf, vt_buf, ctx);
  gemm_bf16<1><<<dim3(6, 64), dim3(256), 0, stream>>>(ctx, wo_t, o_b, 768, 768,
      hidden2, lam1, hs, nullptr, nullptr, nullptr);
  ln_rows<<<dim3(2048), dim3(256), 0, stream>>>(hidden2, ln2_w, ln2_b, y_ln);
  gemm_bf16<2><<<dim3(24, 64), dim3(256), 0, stream>>>(y_ln, wfc1_t, fc1_b, 3072, 768,
      act, nullptr, nullptr, nullptr, nullptr, nullptr);
  gemm_bf16<3><<<dim3(6, 64), dim3(256), 0, stream>>>(act, wfc2_t, fc2_b, 768, 3072,
      d_out, lam2, hidden2, nullptr, nullptr, nullptr);
}